// Round 15
// baseline (68.549 us; speedup 1.0000x reference)
//
#include <hip/hip_runtime.h>
#include <hip/hip_bf16.h>

typedef __attribute__((ext_vector_type(8))) short s16x8;
typedef __attribute__((ext_vector_type(4))) float f32x4;

#define NSLOT 128

__device__ __forceinline__ short f2bf(float f) {
    union { float f; unsigned u; } c; c.f = f;
    unsigned u = c.u;
    return (short)((u + 0x7fffu + ((u >> 16) & 1u)) >> 16);  // RNE
}
__device__ __forceinline__ unsigned pk2(float lo, float hi) {
    __hip_bfloat162 p = __float22bfloat162_rn(make_float2(lo, hi));
    return *reinterpret_cast<unsigned*>(&p);
}
// sum over the 16-lane DPP row via row_ror butterfly (VALU only, no DS pipe)
__device__ __forceinline__ float rowsum16(float x) {
    union { float f; int i; } a, b;
    a.f = x;
    b.i = __builtin_amdgcn_mov_dpp(a.i, 0x121, 0xf, 0xf, true); a.f += b.f; // ror:1
    b.i = __builtin_amdgcn_mov_dpp(a.i, 0x122, 0xf, 0xf, true); a.f += b.f; // ror:2
    b.i = __builtin_amdgcn_mov_dpp(a.i, 0x124, 0xf, 0xf, true); a.f += b.f; // ror:4
    b.i = __builtin_amdgcn_mov_dpp(a.i, 0x128, 0xf, 0xf, true); a.f += b.f; // ror:8
    return a.f;
}

// ---------------------------------------------------------------------------
// K1: precompute (unchanged, proven).
//   blocks 0..63:   UV GEMM (W1 col-slice in regs, x-tile in LDS)
//   block 64:       c0 = q@W1q + g_b1 ; q_exp = relu(relu(q@qe_w1+b1)@qe_w2+b2)
//   blocks 65..96:  w2s swizzle (coalesced reads, scatter bf16 writes)
//   blocks 97..113: zero accb
// ---------------------------------------------------------------------------
__global__ __launch_bounds__(256) void rn_k1(
    const float* __restrict__ x, const float* __restrict__ q,
    const float* __restrict__ g_w1, const float* __restrict__ g_b1,
    const float* __restrict__ g_w2,
    const float* __restrict__ qe_w1, const float* __restrict__ qe_b1,
    const float* __restrict__ qe_w2, const float* __restrict__ qe_b2,
    float* __restrict__ U, float* __restrict__ V,
    float* __restrict__ c0, float* __restrict__ qexp,
    short* __restrict__ w2s, float* __restrict__ accb)
{
    const int blk = blockIdx.x, t = threadIdx.x;

    if (blk < 64) {
        __shared__ float xs[1024];          // 16 rows x 64
        const int rg = blk >> 1, half = blk & 1;
        const int r0 = rg << 4;
        #pragma unroll
        for (int i = 0; i < 4; ++i) {
            int idx = i * 256 + t;
            xs[idx] = x[(r0 << 6) + idx];
        }
        float w[64];
        #pragma unroll
        for (int k = 0; k < 64; ++k)
            w[k] = g_w1[(half * 64 + k) * 256 + t];
        __syncthreads();
        float* dst = half ? V : U;
        #pragma unroll 2
        for (int r = 0; r < 16; ++r) {
            float a0 = 0.f, a1 = 0.f, a2 = 0.f, a3 = 0.f;
            #pragma unroll
            for (int k = 0; k < 64; k += 4) {
                const float4 xv = *(const float4*)&xs[r * 64 + k];
                a0 += xv.x * w[k + 0];
                a1 += xv.y * w[k + 1];
                a2 += xv.z * w[k + 2];
                a3 += xv.w * w[k + 3];
            }
            dst[(r0 + r) * 256 + t] = (a0 + a1) + (a2 + a3);
        }
    } else if (blk == 64) {
        __shared__ float sbuf[64];
        __shared__ float qh[256];
        if (t < 64) sbuf[t] = q[t];
        __syncthreads();
        float cc = g_b1[t], hh = qe_b1[t];
        #pragma unroll 4
        for (int k = 0; k < 64; ++k) {
            float qv = sbuf[k];
            cc += qv * g_w1[(128 + k) * 256 + t];
            hh += qv * qe_w1[k * 256 + t];
        }
        c0[t] = cc;
        qh[t] = fmaxf(hh, 0.f);
        __syncthreads();
        float qe = qe_b2[t];
        #pragma unroll 4
        for (int k = 0; k < 256; ++k) qe += qh[k] * qe_w2[k * 256 + t];
        qexp[t] = fmaxf(qe, 0.f);
    } else if (blk < 97) {
        const int S0 = (blk - 65) * 2048 + t * 8;
        const float4 wA = *(const float4*)&g_w2[S0];
        const float4 wB = *(const float4*)&g_w2[S0 + 4];
        float wv8[8] = {wA.x, wA.y, wA.z, wA.w, wB.x, wB.y, wB.z, wB.w};
        #pragma unroll
        for (int i = 0; i < 8; ++i) {
            const int S = S0 + i;
            const int k = S >> 8, col = S & 255;
            const int wv = col >> 6, n = (col >> 4) & 3, l15 = col & 15;
            const int kk = k >> 5, g = (k >> 3) & 3, e = k & 7;
            const int lane = g * 16 + l15;
            w2s[((((wv * 8 + kk) * 4 + n) * 64 + lane) << 3) + e] = f2bf(wv8[i]);
        }
    } else {
        const int total = NSLOT * 257;
        int off = (blk - 97) * 2048 + t * 8;
        #pragma unroll
        for (int i = 0; i < 8; ++i)
            if (off + i < total) accb[off + i] = 0.f;
    }
}

// ---------------------------------------------------------------------------
// K2: R4's best-measured shape (4096 blocks, 1 unit, launch_bounds(256,4),
// 2 barriers, per-unit atomics) + XOR-swizzled hT:
//   elem (row,col) at row*256 + (col ^ ((row&7)<<3))    [flat, no pad, 32KB]
// afr b128 reads: 8 lanes x 4 dwords cover all 32 banks, l15 8..15 repeat
// -> 2-way only (free per m136). Build writes: same row per 64 lanes ->
// XOR is a permutation -> conflict-free. Kills the invariant 2.1M conflict.
// ---------------------------------------------------------------------------
__global__ __launch_bounds__(256, 4) void rn_k2(
    const float* __restrict__ U, const float* __restrict__ V,
    const float* __restrict__ c0, const float* __restrict__ qexp,
    const short* __restrict__ w2s, const float* __restrict__ g_b2,
    float* __restrict__ accb)
{
    __shared__ short hT[16384];            // 32KB, XOR-swizzled image
    __shared__ float srowT[64][4];         // [row][wave]

    const int bid = blockIdx.x;
    const int a   = bid >> 3;
    const int b0  = (bid & 7) << 6;
    const int tid = threadIdx.x;
    const int wave = tid >> 6, lane = tid & 63;
    const int l15 = lane & 15, g = lane >> 4;
    const int col0 = wave << 6;

    float qe[4], b2c[4];
    #pragma unroll
    for (int n = 0; n < 4; ++n) {
        int col = col0 + n * 16 + l15;
        qe[n]  = qexp[col];
        b2c[n] = g_b2[col];
    }

    // ---- build h tile: 64 rows x 256 cols (bf16, swizzled) ----
    {
        const int c4 = tid & 63;
        const int r0 = tid >> 6;
        const float4 vv  = *(const float4*)&V[a * 256 + c4 * 4];
        const float4 cc  = *(const float4*)&c0[c4 * 4];
        const float4 vcv = make_float4(vv.x + cc.x, vv.y + cc.y,
                                       vv.z + cc.z, vv.w + cc.w);
        #pragma unroll
        for (int it = 0; it < 16; ++it) {
            const int row = r0 + it * 4;
            const float4 uu = *(const float4*)&U[(b0 + row) * 256 + c4 * 4];
            uint2 st;
            st.x = pk2(fmaxf(uu.x + vcv.x, 0.f), fmaxf(uu.y + vcv.y, 0.f));
            st.y = pk2(fmaxf(uu.z + vcv.z, 0.f), fmaxf(uu.w + vcv.w, 0.f));
            const int si = row * 256 + ((c4 * 4) ^ ((row & 7) << 3));
            *reinterpret_cast<uint2*>(&hT[si]) = st;
        }
    }
    __syncthreads();                        // hT ready

    // ---- MFMA: r = h @ W2 + b2 (bias via acc init), B streamed from L2 ----
    const int axor  = (l15 & 7) << 3;
    const int arow0 = l15 * 256;

    f32x4 acc[4][4];
    #pragma unroll
    for (int m = 0; m < 4; ++m)
        #pragma unroll
        for (int n = 0; n < 4; ++n)
            acc[m][n] = (f32x4){b2c[n], b2c[n], b2c[n], b2c[n]};

    #pragma unroll
    for (int kk = 0; kk < 8; ++kk) {
        const int koff = kk * 32 + g * 8;
        s16x8 bfr[4];
        #pragma unroll
        for (int n = 0; n < 4; ++n)
            bfr[n] = *(const s16x8*)&w2s[(wave << 14) + ((kk * 4 + n) << 9) + (lane << 3)];
        s16x8 afr[4];
        #pragma unroll
        for (int m = 0; m < 4; ++m)
            afr[m] = *(const s16x8*)&hT[arow0 + m * 4096 + (koff ^ axor)];
        __builtin_amdgcn_s_setprio(1);
        #pragma unroll
        for (int m = 0; m < 4; ++m)
            #pragma unroll
            for (int n = 0; n < 4; ++n)
                acc[m][n] = __builtin_amdgcn_mfma_f32_16x16x32_bf16(
                    afr[m], bfr[n], acc[m][n], 0, 0, 0);
        __builtin_amdgcn_s_setprio(0);
    }

    // ---- epilogue: relu, DPP score partials ----
    #pragma unroll
    for (int m = 0; m < 4; ++m)
        #pragma unroll
        for (int n = 0; n < 4; ++n)
            #pragma unroll
            for (int j = 0; j < 4; ++j)
                acc[m][n][j] = fmaxf(acc[m][n][j], 0.f);

    #pragma unroll
    for (int m = 0; m < 4; ++m) {
        #pragma unroll
        for (int j = 0; j < 4; ++j) {
            float sp = acc[m][0][j] * qe[0] + acc[m][1][j] * qe[1]
                     + acc[m][2][j] * qe[2] + acc[m][3][j] * qe[3];
            sp = rowsum16(sp);
            if (l15 == 0) srowT[m * 16 + g * 4 + j][wave] = sp;
        }
    }
    __syncthreads();                        // srowT ready

    // ---- exp weights (float4 broadcast reads) + weighted sums + atomics ----
    float wrow[4][4];
    #pragma unroll
    for (int m = 0; m < 4; ++m)
        #pragma unroll
        for (int j = 0; j < 4; ++j) {
            const float4 s4 = *(const float4*)&srowT[m * 16 + g * 4 + j][0];
            wrow[m][j] = __builtin_amdgcn_exp2f(
                (s4.x + s4.y + s4.z + s4.w) * 1.4426950408889634f);
        }

    const int slot = bid & (NSLOT - 1);
    if (wave == 0) {
        float ls = 0.f;
        #pragma unroll
        for (int m = 0; m < 4; ++m)
            #pragma unroll
            for (int j = 0; j < 4; ++j) ls += wrow[m][j];
        ls += __shfl_xor(ls, 16);
        ls += __shfl_xor(ls, 32);           // sum over the 4 g-groups
        if (lane == 0) atomicAdd(&accb[slot * 257 + 256], ls);
    }

    #pragma unroll
    for (int n = 0; n < 4; ++n) {
        float wv = 0.f;
        #pragma unroll
        for (int m = 0; m < 4; ++m)
            #pragma unroll
            for (int j = 0; j < 4; ++j)
                wv += wrow[m][j] * acc[m][n][j];
        wv += __shfl_xor(wv, 16);
        wv += __shfl_xor(wv, 32);
        if (lane < 16) atomicAdd(&accb[slot * 257 + col0 + n * 16 + lane], wv);
    }
}

// ---------------------------------------------------------------------------
// K4: merge NSLOT slots -> embedding -> f MLP -> out[64] (1024 thr, K-split)
// ---------------------------------------------------------------------------
__global__ __launch_bounds__(1024) void rn_k4(
    const float* __restrict__ accb,
    const float* __restrict__ f_w1, const float* __restrict__ f_b1,
    const float* __restrict__ f_w2, const float* __restrict__ f_b2,
    float* __restrict__ out)
{
    __shared__ float part[4][256];
    __shared__ float emb[256];
    __shared__ float fh[256];
    __shared__ float lsa[128];
    const int t   = threadIdx.x;
    const int col = t & 255;
    const int sl  = t >> 8;                 // 0..3

    float v = 0.f;
    #pragma unroll 8
    for (int s = sl; s < NSLOT; s += 4) v += accb[s * 257 + col];
    part[sl][col] = v;
    if (t < 128) lsa[t] = accb[t * 257 + 256];
    __syncthreads();

    if (sl == 0) {
        float ls = 0.f;
        #pragma unroll 8
        for (int s = 0; s < 128; ++s) ls += lsa[s];
        emb[col] = (part[0][col] + part[1][col] + part[2][col] + part[3][col]) / ls;
    }
    __syncthreads();

    {
        float h = 0.f;
        const int k0 = sl << 6;
        #pragma unroll 8
        for (int k = 0; k < 64; ++k)
            h += emb[k0 + k] * f_w1[(k0 + k) * 256 + col];
        part[sl][col] = h;
    }
    __syncthreads();
    if (sl == 0)
        fh[col] = fmaxf(part[0][col] + part[1][col] + part[2][col] + part[3][col]
                        + f_b1[col], 0.f);
    __syncthreads();

    if (t < 256) {
        const int oc = t & 63, ks = t >> 6;
        float o = 0.f;
        const int k0 = ks << 6;
        #pragma unroll 8
        for (int k = 0; k < 64; ++k)
            o += fh[k0 + k] * f_w2[(k0 + k) * 64 + oc];
        part[ks][oc] = o;
    }
    __syncthreads();
    if (t < 64)
        out[t] = part[0][t] + part[1][t] + part[2][t] + part[3][t] + f_b2[t];
}

extern "C" void kernel_launch(void* const* d_in, const int* in_sizes, int n_in,
                              void* d_out, int out_size, void* d_ws, size_t ws_size,
                              hipStream_t stream) {
    const float* x     = (const float*)d_in[0];
    const float* q     = (const float*)d_in[1];
    const float* g_w1  = (const float*)d_in[2];
    const float* g_b1  = (const float*)d_in[3];
    const float* g_w2  = (const float*)d_in[4];
    const float* g_b2  = (const float*)d_in[5];
    const float* qe_w1 = (const float*)d_in[6];
    const float* qe_b1 = (const float*)d_in[7];
    const float* qe_w2 = (const float*)d_in[8];
    const float* qe_b2 = (const float*)d_in[9];
    const float* f_w1  = (const float*)d_in[10];
    const float* f_b1  = (const float*)d_in[11];
    const float* f_w2  = (const float*)d_in[12];
    const float* f_b2  = (const float*)d_in[13];

    float* wsf  = (float*)d_ws;
    float* U    = wsf;                     // 512*256 f32
    float* V    = wsf + 131072;            // 512*256 f32
    float* c0   = wsf + 262144;            // 256
    float* qexp = wsf + 262400;            // 256
    short* w2s  = (short*)(wsf + 262656);  // 256*256 bf16 (swizzled)
    float* accb = wsf + 295424;            // NSLOT slots * 257 floats

    hipLaunchKernelGGL(rn_k1, dim3(114), dim3(256), 0, stream,
                       x, q, g_w1, g_b1, g_w2, qe_w1, qe_b1, qe_w2, qe_b2,
                       U, V, c0, qexp, w2s, accb);
    hipLaunchKernelGGL(rn_k2, dim3(4096), dim3(256), 0, stream,
                       U, V, c0, qexp, (const short*)w2s, g_b2, accb);
    hipLaunchKernelGGL(rn_k4, dim3(1), dim3(1024), 0, stream,
                       accb, f_w1, f_b1, f_w2, f_b2, (float*)d_out);
}

// Round 16
// 66.835 us; speedup vs baseline: 1.0257x; 1.0257x over previous
//
#include <hip/hip_runtime.h>
#include <hip/hip_bf16.h>

typedef __attribute__((ext_vector_type(8))) short s16x8;
typedef __attribute__((ext_vector_type(4))) float f32x4;

#define NSLOT 128

__device__ __forceinline__ short f2bf(float f) {
    union { float f; unsigned u; } c; c.f = f;
    unsigned u = c.u;
    return (short)((u + 0x7fffu + ((u >> 16) & 1u)) >> 16);  // RNE
}
__device__ __forceinline__ unsigned pk2(float lo, float hi) {
    __hip_bfloat162 p = __float22bfloat162_rn(make_float2(lo, hi));
    return *reinterpret_cast<unsigned*>(&p);
}
// sum over the 16-lane DPP row via row_ror butterfly (VALU only, no DS pipe)
__device__ __forceinline__ float rowsum16(float x) {
    union { float f; int i; } a, b;
    a.f = x;
    b.i = __builtin_amdgcn_mov_dpp(a.i, 0x121, 0xf, 0xf, true); a.f += b.f; // ror:1
    b.i = __builtin_amdgcn_mov_dpp(a.i, 0x122, 0xf, 0xf, true); a.f += b.f; // ror:2
    b.i = __builtin_amdgcn_mov_dpp(a.i, 0x124, 0xf, 0xf, true); a.f += b.f; // ror:4
    b.i = __builtin_amdgcn_mov_dpp(a.i, 0x128, 0xf, 0xf, true); a.f += b.f; // ror:8
    return a.f;
}

// ---------------------------------------------------------------------------
// K1: precompute (unchanged, proven).
// ---------------------------------------------------------------------------
__global__ __launch_bounds__(256) void rn_k1(
    const float* __restrict__ x, const float* __restrict__ q,
    const float* __restrict__ g_w1, const float* __restrict__ g_b1,
    const float* __restrict__ g_w2,
    const float* __restrict__ qe_w1, const float* __restrict__ qe_b1,
    const float* __restrict__ qe_w2, const float* __restrict__ qe_b2,
    float* __restrict__ U, float* __restrict__ V,
    float* __restrict__ c0, float* __restrict__ qexp,
    short* __restrict__ w2s, float* __restrict__ accb)
{
    const int blk = blockIdx.x, t = threadIdx.x;

    if (blk < 64) {
        __shared__ float xs[1024];          // 16 rows x 64
        const int rg = blk >> 1, half = blk & 1;
        const int r0 = rg << 4;
        #pragma unroll
        for (int i = 0; i < 4; ++i) {
            int idx = i * 256 + t;
            xs[idx] = x[(r0 << 6) + idx];
        }
        float w[64];
        #pragma unroll
        for (int k = 0; k < 64; ++k)
            w[k] = g_w1[(half * 64 + k) * 256 + t];
        __syncthreads();
        float* dst = half ? V : U;
        #pragma unroll 2
        for (int r = 0; r < 16; ++r) {
            float a0 = 0.f, a1 = 0.f, a2 = 0.f, a3 = 0.f;
            #pragma unroll
            for (int k = 0; k < 64; k += 4) {
                const float4 xv = *(const float4*)&xs[r * 64 + k];
                a0 += xv.x * w[k + 0];
                a1 += xv.y * w[k + 1];
                a2 += xv.z * w[k + 2];
                a3 += xv.w * w[k + 3];
            }
            dst[(r0 + r) * 256 + t] = (a0 + a1) + (a2 + a3);
        }
    } else if (blk == 64) {
        __shared__ float sbuf[64];
        __shared__ float qh[256];
        if (t < 64) sbuf[t] = q[t];
        __syncthreads();
        float cc = g_b1[t], hh = qe_b1[t];
        #pragma unroll 4
        for (int k = 0; k < 64; ++k) {
            float qv = sbuf[k];
            cc += qv * g_w1[(128 + k) * 256 + t];
            hh += qv * qe_w1[k * 256 + t];
        }
        c0[t] = cc;
        qh[t] = fmaxf(hh, 0.f);
        __syncthreads();
        float qe = qe_b2[t];
        #pragma unroll 4
        for (int k = 0; k < 256; ++k) qe += qh[k] * qe_w2[k * 256 + t];
        qexp[t] = fmaxf(qe, 0.f);
    } else if (blk < 97) {
        const int S0 = (blk - 65) * 2048 + t * 8;
        const float4 wA = *(const float4*)&g_w2[S0];
        const float4 wB = *(const float4*)&g_w2[S0 + 4];
        float wv8[8] = {wA.x, wA.y, wA.z, wA.w, wB.x, wB.y, wB.z, wB.w};
        #pragma unroll
        for (int i = 0; i < 8; ++i) {
            const int S = S0 + i;
            const int k = S >> 8, col = S & 255;
            const int wv = col >> 6, n = (col >> 4) & 3, l15 = col & 15;
            const int kk = k >> 5, g = (k >> 3) & 3, e = k & 7;
            const int lane = g * 16 + l15;
            w2s[((((wv * 8 + kk) * 4 + n) * 64 + lane) << 3) + e] = f2bf(wv8[i]);
        }
    } else {
        const int total = NSLOT * 257;
        int off = (blk - 97) * 2048 + t * 8;
        #pragma unroll
        for (int i = 0; i < 8; ++i)
            if (off + i < total) accb[off + i] = 0.f;
    }
}

// ---------------------------------------------------------------------------
// K2: R15 structure (4096 blocks, 1 unit, launch_bounds(256,4), XOR-swizzled
// hT, 2 barriers, per-unit atomics) + PACKED-F32 VALU: all build/relu/score/
// weighted-sum arithmetic as f32x4 vector ops -> v_pk_{add,max,fma}_f32,
// ~halving the scalar VALU instruction count (the binding 48% pipe).
// ---------------------------------------------------------------------------
__global__ __launch_bounds__(256, 4) void rn_k2(
    const float* __restrict__ U, const float* __restrict__ V,
    const float* __restrict__ c0, const float* __restrict__ qexp,
    const short* __restrict__ w2s, const float* __restrict__ g_b2,
    float* __restrict__ accb)
{
    __shared__ short hT[16384];            // 32KB, XOR-swizzled image
    __shared__ float srowT[64][4];         // [row][wave]

    const int bid = blockIdx.x;
    const int a   = bid >> 3;
    const int b0  = (bid & 7) << 6;
    const int tid = threadIdx.x;
    const int wave = tid >> 6, lane = tid & 63;
    const int l15 = lane & 15, g = lane >> 4;
    const int col0 = wave << 6;

    const f32x4 zero4 = (f32x4){0.f, 0.f, 0.f, 0.f};

    float qe[4], b2c[4];
    #pragma unroll
    for (int n = 0; n < 4; ++n) {
        int col = col0 + n * 16 + l15;
        qe[n]  = qexp[col];
        b2c[n] = g_b2[col];
    }

    // ---- build h tile: 64 rows x 256 cols (bf16, swizzled, packed math) ----
    {
        const int c4 = tid & 63;
        const int r0 = tid >> 6;
        const f32x4 vv  = *(const f32x4*)&V[a * 256 + c4 * 4];
        const f32x4 cc  = *(const f32x4*)&c0[c4 * 4];
        const f32x4 vcv = vv + cc;                       // pk_add
        #pragma unroll
        for (int it = 0; it < 16; ++it) {
            const int row = r0 + it * 4;
            const f32x4 uu = *(const f32x4*)&U[(b0 + row) * 256 + c4 * 4];
            const f32x4 h4 = __builtin_elementwise_max(uu + vcv, zero4); // pk
            uint2 st;
            st.x = pk2(h4[0], h4[1]);
            st.y = pk2(h4[2], h4[3]);
            const int si = row * 256 + ((c4 * 4) ^ ((row & 7) << 3));
            *reinterpret_cast<uint2*>(&hT[si]) = st;
        }
    }
    __syncthreads();                        // hT ready

    // ---- MFMA: r = h @ W2 + b2 (bias via acc init), B streamed from L2 ----
    const int axor  = (l15 & 7) << 3;
    const int arow0 = l15 * 256;

    f32x4 acc[4][4];
    #pragma unroll
    for (int m = 0; m < 4; ++m)
        #pragma unroll
        for (int n = 0; n < 4; ++n)
            acc[m][n] = (f32x4){b2c[n], b2c[n], b2c[n], b2c[n]};

    #pragma unroll
    for (int kk = 0; kk < 8; ++kk) {
        const int koff = kk * 32 + g * 8;
        s16x8 bfr[4];
        #pragma unroll
        for (int n = 0; n < 4; ++n)
            bfr[n] = *(const s16x8*)&w2s[(wave << 14) + ((kk * 4 + n) << 9) + (lane << 3)];
        s16x8 afr[4];
        #pragma unroll
        for (int m = 0; m < 4; ++m)
            afr[m] = *(const s16x8*)&hT[arow0 + m * 4096 + (koff ^ axor)];
        __builtin_amdgcn_s_setprio(1);
        #pragma unroll
        for (int m = 0; m < 4; ++m)
            #pragma unroll
            for (int n = 0; n < 4; ++n)
                acc[m][n] = __builtin_amdgcn_mfma_f32_16x16x32_bf16(
                    afr[m], bfr[n], acc[m][n], 0, 0, 0);
        __builtin_amdgcn_s_setprio(0);
    }

    // ---- epilogue: relu (pk-max), score partials (pk-fma + DPP) ----
    #pragma unroll
    for (int m = 0; m < 4; ++m)
        #pragma unroll
        for (int n = 0; n < 4; ++n)
            acc[m][n] = __builtin_elementwise_max(acc[m][n], zero4);

    #pragma unroll
    for (int m = 0; m < 4; ++m) {
        f32x4 spv = acc[m][0] * qe[0];
        spv += acc[m][1] * qe[1];
        spv += acc[m][2] * qe[2];
        spv += acc[m][3] * qe[3];           // pk-fma, j packed
        #pragma unroll
        for (int j = 0; j < 4; ++j) {
            const float sp = rowsum16(spv[j]);
            if (l15 == 0) srowT[m * 16 + g * 4 + j][wave] = sp;
        }
    }
    __syncthreads();                        // srowT ready

    // ---- exp weights + weighted sums (pk-fma) + atomics ----
    f32x4 wrowv[4];
    #pragma unroll
    for (int m = 0; m < 4; ++m)
        #pragma unroll
        for (int j = 0; j < 4; ++j) {
            const float4 s4 = *(const float4*)&srowT[m * 16 + g * 4 + j][0];
            wrowv[m][j] = __builtin_amdgcn_exp2f(
                (s4.x + s4.y + s4.z + s4.w) * 1.4426950408889634f);
        }

    const int slot = bid & (NSLOT - 1);
    if (wave == 0) {
        const f32x4 lsv = (wrowv[0] + wrowv[1]) + (wrowv[2] + wrowv[3]);
        float ls = (lsv[0] + lsv[1]) + (lsv[2] + lsv[3]);
        ls += __shfl_xor(ls, 16);
        ls += __shfl_xor(ls, 32);           // sum over the 4 g-groups
        if (lane == 0) atomicAdd(&accb[slot * 257 + 256], ls);
    }

    #pragma unroll
    for (int n = 0; n < 4; ++n) {
        f32x4 wvv = wrowv[0] * acc[0][n];
        wvv += wrowv[1] * acc[1][n];
        wvv += wrowv[2] * acc[2][n];
        wvv += wrowv[3] * acc[3][n];        // pk-fma, j packed
        float wv = (wvv[0] + wvv[1]) + (wvv[2] + wvv[3]);
        wv += __shfl_xor(wv, 16);
        wv += __shfl_xor(wv, 32);
        if (lane < 16) atomicAdd(&accb[slot * 257 + col0 + n * 16 + lane], wv);
    }
}

// ---------------------------------------------------------------------------
// K4: merge NSLOT slots -> embedding -> f MLP -> out[64] (1024 thr, K-split)
// ---------------------------------------------------------------------------
__global__ __launch_bounds__(1024) void rn_k4(
    const float* __restrict__ accb,
    const float* __restrict__ f_w1, const float* __restrict__ f_b1,
    const float* __restrict__ f_w2, const float* __restrict__ f_b2,
    float* __restrict__ out)
{
    __shared__ float part[4][256];
    __shared__ float emb[256];
    __shared__ float fh[256];
    __shared__ float lsa[128];
    const int t   = threadIdx.x;
    const int col = t & 255;
    const int sl  = t >> 8;                 // 0..3

    float v = 0.f;
    #pragma unroll 8
    for (int s = sl; s < NSLOT; s += 4) v += accb[s * 257 + col];
    part[sl][col] = v;
    if (t < 128) lsa[t] = accb[t * 257 + 256];
    __syncthreads();

    if (sl == 0) {
        float ls = 0.f;
        #pragma unroll 8
        for (int s = 0; s < 128; ++s) ls += lsa[s];
        emb[col] = (part[0][col] + part[1][col] + part[2][col] + part[3][col]) / ls;
    }
    __syncthreads();

    {
        float h = 0.f;
        const int k0 = sl << 6;
        #pragma unroll 8
        for (int k = 0; k < 64; ++k)
            h += emb[k0 + k] * f_w1[(k0 + k) * 256 + col];
        part[sl][col] = h;
    }
    __syncthreads();
    if (sl == 0)
        fh[col] = fmaxf(part[0][col] + part[1][col] + part[2][col] + part[3][col]
                        + f_b1[col], 0.f);
    __syncthreads();

    if (t < 256) {
        const int oc = t & 63, ks = t >> 6;
        float o = 0.f;
        const int k0 = ks << 6;
        #pragma unroll 8
        for (int k = 0; k < 64; ++k)
            o += fh[k0 + k] * f_w2[(k0 + k) * 64 + oc];
        part[ks][oc] = o;
    }
    __syncthreads();
    if (t < 64)
        out[t] = part[0][t] + part[1][t] + part[2][t] + part[3][t] + f_b2[t];
}

extern "C" void kernel_launch(void* const* d_in, const int* in_sizes, int n_in,
                              void* d_out, int out_size, void* d_ws, size_t ws_size,
                              hipStream_t stream) {
    const float* x     = (const float*)d_in[0];
    const float* q     = (const float*)d_in[1];
    const float* g_w1  = (const float*)d_in[2];
    const float* g_b1  = (const float*)d_in[3];
    const float* g_w2  = (const float*)d_in[4];
    const float* g_b2  = (const float*)d_in[5];
    const float* qe_w1 = (const float*)d_in[6];
    const float* qe_b1 = (const float*)d_in[7];
    const float* qe_w2 = (const float*)d_in[8];
    const float* qe_b2 = (const float*)d_in[9];
    const float* f_w1  = (const float*)d_in[10];
    const float* f_b1  = (const float*)d_in[11];
    const float* f_w2  = (const float*)d_in[12];
    const float* f_b2  = (const float*)d_in[13];

    float* wsf  = (float*)d_ws;
    float* U    = wsf;                     // 512*256 f32
    float* V    = wsf + 131072;            // 512*256 f32
    float* c0   = wsf + 262144;            // 256
    float* qexp = wsf + 262400;            // 256
    short* w2s  = (short*)(wsf + 262656);  // 256*256 bf16 (swizzled)
    float* accb = wsf + 295424;            // NSLOT slots * 257 floats

    hipLaunchKernelGGL(rn_k1, dim3(114), dim3(256), 0, stream,
                       x, q, g_w1, g_b1, g_w2, qe_w1, qe_b1, qe_w2, qe_b2,
                       U, V, c0, qexp, w2s, accb);
    hipLaunchKernelGGL(rn_k2, dim3(4096), dim3(256), 0, stream,
                       U, V, c0, qexp, (const short*)w2s, g_b2, accb);
    hipLaunchKernelGGL(rn_k4, dim3(1), dim3(1024), 0, stream,
                       accb, f_w1, f_b1, f_w2, f_b2, (float*)d_out);
}